// Round 5
// baseline (218.399 us; speedup 1.0000x reference)
//
#include <hip/hip_runtime.h>
#include <cstddef>

#define B_   16
#define C_   256
#define HW_  4096

typedef __attribute__((ext_vector_type(8)))  short bf16x8;
typedef __attribute__((ext_vector_type(16))) float f32x16;

static __device__ __forceinline__ unsigned short f2bf(float f) {
    unsigned int u = __float_as_uint(f);
    u += 0x7fffu + ((u >> 16) & 1u);          // RNE
    return (unsigned short)(u >> 16);
}

// ---------------------------------------------------------------------------
// Kernel E: fused square + NCHW->NHWC bf16 + per-(b,q,h) energy argmax
// partials. grid = (b,h) = 1024 blocks x 256 thr.
// ---------------------------------------------------------------------------
__global__ __launch_bounds__(256) void fused_energy(const float* __restrict__ x,
                                                    unsigned short* __restrict__ xsqN,
                                                    float* __restrict__ pval,
                                                    int* __restrict__ pidx) {
    int blk = blockIdx.x;
    int b = blk >> 6, h = blk & 63;
    int tid = threadIdx.x;
    int w = tid & 63, layer = tid >> 6;
    __shared__ float earr[4][4][64];
    __shared__ unsigned short tile[64][264];   // row stride 264 ush = 528B (16B-mult, bank-spread)
    float e0 = 0.f, e1 = 0.f, e2 = 0.f, e3 = 0.f;
    const float* xb = x + (size_t)b * C_ * HW_ + h * 64 + w;
#pragma unroll
    for (int i = 0; i < 8; ++i) {
        int c0 = (i * 4 + layer) * 8;
        union { unsigned short us[8]; int4 v; } u;
        float es = 0.f;
#pragma unroll
        for (int k = 0; k < 8; ++k) {
            float v = xb[(size_t)(c0 + k) * HW_];
            float s = v * v;
            es += s;
            u.us[k] = f2bf(s);
        }
        *(int4*)&tile[w][c0] = u.v;
        if ((i >> 1) == 0) e0 += es;
        else if ((i >> 1) == 1) e1 += es;
        else if ((i >> 1) == 2) e2 += es;
        else e3 += es;
    }
    earr[layer][0][w] = e0; earr[layer][1][w] = e1;
    earr[layer][2][w] = e2; earr[layer][3][w] = e3;
    __syncthreads();
    // contiguous NHWC stores: 32 lanes cover one 512B row segment
    size_t base = (size_t)(b * 64 + h) * 64 * 256;
#pragma unroll
    for (int it = 0; it < 8; ++it) {
        int row  = it * 8 + (tid >> 5);
        int col8 = (tid & 31) * 8;
        *(int4*)(xsqN + base + (size_t)row * 256 + col8) = *(int4*)&tile[row][col8];
    }
    int q = tid >> 6;
    float ev = earr[0][q][w] + earr[1][q][w] + earr[2][q][w] + earr[3][q][w];
    int ix = h * 64 + w;
#pragma unroll
    for (int off = 32; off; off >>= 1) {
        float ov = __shfl_down(ev, off);
        int   oi = __shfl_down(ix, off);
        if (ov > ev || (ov == ev && oi < ix)) { ev = ov; ix = oi; }
    }
    if ((tid & 63) == 0) {
        pval[(b * 64 + h) * 4 + q] = ev;
        pidx[(b * 64 + h) * 4 + q] = ix;
    }
}

// ---------------------------------------------------------------------------
// Final argmax over h per (b,q). grid = 64 blocks (b*4+q) x 64 thr.
// ---------------------------------------------------------------------------
__global__ __launch_bounds__(64) void energy_final(const float* __restrict__ pval,
                                                   const int* __restrict__ pidx,
                                                   int* __restrict__ lm) {
    int bq = blockIdx.x;
    int b = bq >> 2, q = bq & 3;
    int h = threadIdx.x;
    float ev = pval[(b * 64 + h) * 4 + q];
    int   ix = pidx[(b * 64 + h) * 4 + q];
#pragma unroll
    for (int off = 32; off; off >>= 1) {
        float ov = __shfl_down(ev, off);
        int   oi = __shfl_down(ix, off);
        if (ov > ev || (ov == ev && oi < ix)) { ev = ov; ix = oi; }
    }
    if (h == 0) lm[bq] = ix;
}

// ---------------------------------------------------------------------------
// Landmark value table Lval[b][c] (bf16). 16 blocks x 256 thr.
// ---------------------------------------------------------------------------
__global__ __launch_bounds__(256) void lval_kernel(const unsigned short* __restrict__ xsqN,
                                                   const int* __restrict__ lm,
                                                   unsigned short* __restrict__ Lval) {
    int t = blockIdx.x * 256 + threadIdx.x;   // b*256 + c
    int b = t >> 8, c = t & 255, q = c >> 6;
    int l = lm[b * 4 + q];
    Lval[t] = xsqN[((size_t)((b * 64 + (l >> 6)) * 64 + (l & 63))) * 256 + c];
}

// ---------------------------------------------------------------------------
// Weight pack -> fragment-ordered bf16 (unchanged, verified).
// Chunk (j,cib) = 16KB contiguous: offset (j*8+cib)*8192 ushorts.
// frag layout: chunk*1024 + (s*8 + g)*64 + lane, g = co/32 in 0..7.
// ---------------------------------------------------------------------------
__global__ __launch_bounds__(64) void wt_pack(const float* __restrict__ w,
                                              unsigned short* __restrict__ wa) {
    int blk  = blockIdx.x;
    int lane = threadIdx.x;
    int cog = blk & 7;
    int s   = (blk >> 3) & 1;
    int cib = (blk >> 4) & 7;
    int j   = blk >> 7;
    int co  = cog * 32 + (lane & 31);
    int k0  = cib * 32 + s * 16 + (lane >> 5) * 8;
    union { unsigned short us[8]; int4 v; } u;
#pragma unroll
    for (int jj = 0; jj < 8; ++jj) {
        int ci = k0 + jj;
        u.us[jj] = f2bf(w[(size_t)(co * 256 + ci) * 9 + j]);
    }
    *(int4*)(wa + ((size_t)blk * 64 + lane) * 8) = u.v;
}

// ---------------------------------------------------------------------------
// B-tile stage: load halo (6 rows x 66 cols x 32 ci) for ci-block nc,
// apply guided rect-max quadrant masking, store to LDS. Transient regs only.
// ---------------------------------------------------------------------------
static __device__ __forceinline__ void stage_B(unsigned short* __restrict__ Bs,
                                               const unsigned short* __restrict__ xsqN,
                                               const unsigned short* __restrict__ Lval,
                                               const int* __restrict__ lm,
                                               int b, int h0, int nc, int tid) {
    int l = lm[b * 4 + (nc >> 1)];
    int hm = l >> 6, wm = l & 63;
    bool qhle = (nc >> 1) < 2;          // quadrants 0,1: h <= hm
    bool qwle = ((nc >> 1) & 1) == 0;   // quadrants 0,2: w <= wm
    int4 sv[4];
#pragma unroll
    for (int t2 = 0; t2 < 4; ++t2) {
        int idx = tid + t2 * 512;
        int4 v = {0, 0, 0, 0};
        if (idx < 1584) {
            int pr = idx / 264; int rem = idx - pr * 264;
            int pc = rem >> 2;  int part = rem & 3;
            int grow = h0 - 1 + pr, gcol = pc - 1;
            if ((unsigned)grow < 64u && (unsigned)gcol < 64u)
                v = *(const int4*)(xsqN + (((size_t)(b * 64 + grow) * 64 + gcol) * 256 + nc * 32 + part * 8));
        }
        sv[t2] = v;
    }
#pragma unroll
    for (int t2 = 0; t2 < 4; ++t2) {
        int idx = tid + t2 * 512;
        if (idx < 1584) {
            int pr = idx / 264; int rem = idx - pr * 264;
            int pc = rem >> 2;  int part = rem & 3;
            int grow = h0 - 1 + pr, gcol = pc - 1;
            union { int4 v; unsigned short us[8]; } u; u.v = sv[t2];
            bool inb = ((unsigned)grow < 64u) && ((unsigned)gcol < 64u);
            bool hok = qhle ? (grow <= hm) : (grow >= hm);
            bool wok = qwle ? (gcol <= wm) : (gcol >= wm);
            if (inb && hok && wok) {
                union { int4 v; unsigned short us[8]; } Lu;
                Lu.v = *(const int4*)(Lval + b * 256 + nc * 32 + part * 8);
#pragma unroll
                for (int k = 0; k < 8; ++k)
                    if (Lu.us[k] > u.us[k]) u.us[k] = Lu.us[k];  // bf16 >=0: bit-compare valid
            }
            *(int4*)(&Bs[(pr * 66 + pc) * 40 + part * 8]) = u.v;
        }
    }
}

// ---------------------------------------------------------------------------
// Conv: implicit-GEMM bf16 MFMA — OCCUPANCY-DOUBLED variant.
//   Diagnosis: matrix-busy is ~31 us (the MFMA floor) in every schedule tried;
//   the ~60 us idle is invariant to barriers/A-source/pipelining -> the bound
//   is 2 lockstep waves/SIMD stalling together. Fix: per-wave acc halved to
//   [2][2] (64 AGPR) so total VGPR <= 128 -> 4 waves/SIMD = 2 blocks/CU.
//   Blocks pt and pt+256 are the two co-halves of the SAME pixel tile: same
//   XCD (pt mod 8 equal), shared B in L1/L2, independent barriers -> one
//   block's staging/barrier/epilogue hides under the other's MFMAs.
//   A: simple per-tap global loads (fragment-ordered, L1/L2-hit).
//   B: single LDS buffer, stage-then-compute per cib (2 barriers/cib; cheap
//   now that another block is resident).
// Block: 512 thr = 8 waves; tile 128co x 256px. Wave: 64co x 64px. Grid 512.
// ---------------------------------------------------------------------------
__global__ __launch_bounds__(512, 4) void conv_mfma(const unsigned short* __restrict__ xsqN,
                                                    const unsigned short* __restrict__ wa,
                                                    const float* __restrict__ bias,
                                                    const int* __restrict__ lm,
                                                    const unsigned short* __restrict__ Lval,
                                                    float* __restrict__ out) {
    int pt   = blockIdx.x;            // ch*256 + b*16 + hq
    int ch   = pt >> 8;               // co half (0: co 0..127, 1: co 128..255)
    int tile = pt & 255;
    int b    = tile >> 4;
    int h0   = (tile & 15) * 4;
    int tid  = threadIdx.x;
    int lane = tid & 63;
    int wv   = tid >> 6;
    int wy = wv >> 2, wx = wv & 3;    // co quarter-within-half / image row
    int l31 = lane & 31, qh = lane >> 5;
    int cq  = ch * 2 + wy;            // global co-quarter 0..3 (64 co each)

    __shared__ unsigned short Bs[6 * 66 * 40];   // 31.7 KB

    f32x16 acc[2][2];
#pragma unroll
    for (int mt = 0; mt < 2; ++mt)
#pragma unroll
        for (int nt = 0; nt < 2; ++nt)
#pragma unroll
            for (int r = 0; r < 16; ++r) acc[mt][nt][r] = 0.f;

    // ---- prologue: stage B(cib=0)
    stage_B(Bs, xsqN, Lval, lm, b, h0, 0, tid);
    __syncthreads();

    // A frag base for this wave (16B frag units):
    //   frag[(j*8+cib)*1024 + (s*8 + cq*2 + m)*64 + lane]
    const bf16x8* Abase = (const bf16x8*)wa + (cq << 7) + lane;

    for (int cib = 0; cib < 8; ++cib) {
#pragma unroll
        for (int j = 0; j < 9; ++j) {
            int j3 = j / 3;
            int r  = wx + j3;                 // dh+1
            int w0 = l31 + (j - j3 * 3);      // dw+1
            const unsigned short* Bp = Bs + (r * 66 + w0) * 40 + qh * 8;
            const bf16x8* Ap = Abase + (((size_t)(j * 8 + cib)) << 10);
#pragma unroll
            for (int s = 0; s < 2; ++s) {
                bf16x8 a0 = Ap[s * 512];
                bf16x8 a1 = Ap[s * 512 + 64];
                bf16x8 b0 = *(const bf16x8*)(Bp + s * 16);
                bf16x8 b1 = *(const bf16x8*)(Bp + 1280 + s * 16);
                acc[0][0] = __builtin_amdgcn_mfma_f32_32x32x16_bf16(a0, b0, acc[0][0], 0, 0, 0);
                acc[0][1] = __builtin_amdgcn_mfma_f32_32x32x16_bf16(a0, b1, acc[0][1], 0, 0, 0);
                acc[1][0] = __builtin_amdgcn_mfma_f32_32x32x16_bf16(a1, b0, acc[1][0], 0, 0, 0);
                acc[1][1] = __builtin_amdgcn_mfma_f32_32x32x16_bf16(a1, b1, acc[1][1], 0, 0, 0);
            }
        }
        if (cib < 7) {
            __syncthreads();                      // all reads of Bs done
            stage_B(Bs, xsqN, Lval, lm, b, h0, cib + 1, tid);
            __syncthreads();                      // Bs[cib+1] ready
        }
    }

    // ---- epilogue ----
    int h = h0 + wx;
#pragma unroll
    for (int mt = 0; mt < 2; ++mt) {
#pragma unroll
        for (int nt = 0; nt < 2; ++nt) {
#pragma unroll
            for (int r = 0; r < 16; ++r) {
                int row = (r & 3) + 8 * (r >> 2) + 4 * qh;
                int co  = cq * 64 + mt * 32 + row;
                int w   = nt * 32 + l31;
                out[(((size_t)(b * 256 + co)) * 64 + h) * 64 + w] = acc[mt][nt][r] + bias[co];
            }
        }
    }
}

// ---------------------------------------------------------------------------
extern "C" void kernel_launch(void* const* d_in, const int* in_sizes, int n_in,
                              void* d_out, int out_size, void* d_ws, size_t ws_size,
                              hipStream_t stream) {
    const float* x      = (const float*)d_in[0];
    const float* weight = (const float*)d_in[1];
    const float* bias   = (const float*)d_in[2];
    float* out = (float*)d_out;

    char* ws = (char*)d_ws;
    int*            lmp  = (int*)ws;                         // 64 ints @0
    float*          pval = (float*)(ws + 256);               // 4096 f
    int*            pidx = (int*)(ws + 256 + 16384);         // 4096 i
    unsigned short* Lval = (unsigned short*)(ws + 256 + 32768);  // 4096 ush
    unsigned short* Wa   = (unsigned short*)(ws + 49152);    // 1.18 MB
    unsigned short* xsqN = (unsigned short*)(ws + 49152 + 1179648); // NHWC bf16 33.55 MB

    hipLaunchKernelGGL(fused_energy, dim3(1024), dim3(256), 0, stream, x, xsqN, pval, pidx);
    hipLaunchKernelGGL(energy_final, dim3(64), dim3(64), 0, stream, pval, pidx, lmp);
    hipLaunchKernelGGL(lval_kernel, dim3(16), dim3(256), 0, stream, xsqN, lmp, Lval);
    hipLaunchKernelGGL(wt_pack, dim3(1152), dim3(64), 0, stream, weight, Wa);
    hipLaunchKernelGGL(conv_mfma, dim3(512), dim3(512), 0, stream, xsqN, Wa, bias, lmp, Lval, out);
}

// Round 6
// 196.240 us; speedup vs baseline: 1.1129x; 1.1129x over previous
//
#include <hip/hip_runtime.h>
#include <cstddef>

#define B_   16
#define C_   256
#define HW_  4096

typedef __attribute__((ext_vector_type(8)))  short bf16x8;
typedef __attribute__((ext_vector_type(16))) float f32x16;

static __device__ __forceinline__ unsigned short f2bf(float f) {
    unsigned int u = __float_as_uint(f);
    u += 0x7fffu + ((u >> 16) & 1u);          // RNE
    return (unsigned short)(u >> 16);
}

// ---------------------------------------------------------------------------
// Kernel E v2: fused square + NCHW->NHWC bf16 + per-(b,q,h) energy argmax
// partials. grid = (b,h) = 1024 blocks x 256 thr.
// v2: float4 loads over w (16B/lane vs 4B scalar), quadrant as compile-time
// loop index, wave-local shfl_xor channel reduction, ushort4 LDS tile writes.
// ---------------------------------------------------------------------------
__global__ __launch_bounds__(256) void fused_energy(const float* __restrict__ x,
                                                    unsigned short* __restrict__ xsqN,
                                                    float* __restrict__ pval,
                                                    int* __restrict__ pidx) {
    int blk = blockIdx.x;
    int b = blk >> 6, h = blk & 63;
    int tid = threadIdx.x;
    int tl  = tid >> 4;           // 0..15 channel-lane group
    int w4  = (tid & 15) << 2;    // w base 0,4,...,60
    int wv  = tid >> 6;           // wave 0..3
    __shared__ float earr[4][4][64];            // [wave][q][w]
    __shared__ unsigned short tile[64][264];    // row stride 264 ush = 528B
    const float* xb = x + (size_t)b * C_ * HW_ + h * 64 + w4;

    float e[4][4];                // [quadrant][ww]
#pragma unroll
    for (int q = 0; q < 4; ++q)
#pragma unroll
        for (int ww = 0; ww < 4; ++ww) e[q][ww] = 0.f;

#pragma unroll
    for (int i = 0; i < 4; ++i) {             // quadrant = i (compile-time)
        int c4 = tl * 4 + 64 * i;             // 4 consecutive channels
        float sq[4][4];                       // [k=channel][ww]
#pragma unroll
        for (int k = 0; k < 4; ++k) {
            float4 v = *(const float4*)(xb + (size_t)(c4 + k) * HW_);
            sq[k][0] = v.x * v.x; sq[k][1] = v.y * v.y;
            sq[k][2] = v.z * v.z; sq[k][3] = v.w * v.w;
            e[i][0] += sq[k][0]; e[i][1] += sq[k][1];
            e[i][2] += sq[k][2]; e[i][3] += sq[k][3];
        }
#pragma unroll
        for (int ww = 0; ww < 4; ++ww) {      // pack 4 channels -> ushort4
            uint2 p;
            p.x = (unsigned)f2bf(sq[0][ww]) | ((unsigned)f2bf(sq[1][ww]) << 16);
            p.y = (unsigned)f2bf(sq[2][ww]) | ((unsigned)f2bf(sq[3][ww]) << 16);
            *(uint2*)(&tile[w4 + ww][c4]) = p;
        }
    }

    // wave-local reduce over the 4 tl-groups within this wave (tid bits 4,5)
#pragma unroll
    for (int q = 0; q < 4; ++q)
#pragma unroll
        for (int ww = 0; ww < 4; ++ww) {
            float v = e[q][ww];
            v += __shfl_xor(v, 16);
            v += __shfl_xor(v, 32);
            e[q][ww] = v;
        }
    if ((tid & 48) == 0) {        // one lane per shfl-group (lanes 0..15 of wave)
#pragma unroll
        for (int q = 0; q < 4; ++q) {
            float4 v; v.x = e[q][0]; v.y = e[q][1]; v.z = e[q][2]; v.w = e[q][3];
            *(float4*)&earr[wv][q][w4] = v;
        }
    }
    __syncthreads();

    // contiguous NHWC stores: 32 lanes cover one 512B row segment
    size_t base = (size_t)(b * 64 + h) * 64 * 256;
#pragma unroll
    for (int it = 0; it < 8; ++it) {
        int row  = it * 8 + (tid >> 5);
        int col8 = (tid & 31) * 8;
        *(int4*)(xsqN + base + (size_t)row * 256 + col8) = *(int4*)&tile[row][col8];
    }

    int q = tid >> 6;
    int w = tid & 63;
    float ev = earr[0][q][w] + earr[1][q][w] + earr[2][q][w] + earr[3][q][w];
    int ix = h * 64 + w;
#pragma unroll
    for (int off = 32; off; off >>= 1) {
        float ov = __shfl_down(ev, off);
        int   oi = __shfl_down(ix, off);
        if (ov > ev || (ov == ev && oi < ix)) { ev = ov; ix = oi; }
    }
    if ((tid & 63) == 0) {
        pval[(b * 64 + h) * 4 + q] = ev;
        pidx[(b * 64 + h) * 4 + q] = ix;
    }
}

// ---------------------------------------------------------------------------
// Final argmax over h per (b,q) FUSED with landmark value gather (one fewer
// launch). grid = 64 blocks (b*4+q) x 64 thr.
// ---------------------------------------------------------------------------
__global__ __launch_bounds__(64) void energy_final(const float* __restrict__ pval,
                                                   const int* __restrict__ pidx,
                                                   int* __restrict__ lm,
                                                   const unsigned short* __restrict__ xsqN,
                                                   unsigned short* __restrict__ Lval) {
    int bq = blockIdx.x;
    int b = bq >> 2, q = bq & 3;
    int t = threadIdx.x;
    float ev = pval[(b * 64 + t) * 4 + q];
    int   ix = pidx[(b * 64 + t) * 4 + q];
#pragma unroll
    for (int off = 32; off; off >>= 1) {
        float ov = __shfl_down(ev, off);
        int   oi = __shfl_down(ix, off);
        if (ov > ev || (ov == ev && oi < ix)) { ev = ov; ix = oi; }
    }
    int ix0 = __shfl(ix, 0);
    if (t == 0) lm[bq] = ix0;
    // Lval[b][q*64+t] = xsqN at landmark pixel, channel q*64+t
    Lval[b * 256 + q * 64 + t] =
        xsqN[((size_t)((b * 64 + (ix0 >> 6)) * 64 + (ix0 & 63))) * 256 + q * 64 + t];
}

// ---------------------------------------------------------------------------
// Weight pack v2 -> fragment-ordered bf16, same output layout as before
// (verified index algebra), but with fully-coalesced float4 reads through an
// LDS bf16 transpose. Old version gathered stride-36B scalars across 9.2KB
// lane strides (~16x overfetch). grid = 64 blocks (cog*8+cib) x 256 thr.
// ---------------------------------------------------------------------------
__global__ __launch_bounds__(256) void wt_pack(const float* __restrict__ w,
                                               unsigned short* __restrict__ wa) {
    int blk = blockIdx.x;
    int cog = blk >> 3, cib = blk & 7;
    int tid = threadIdx.x;
    __shared__ unsigned short wlds[32][292];   // [co_l][cc*9+j], pad 288->292
    {
        int co_l = tid >> 3;          // 0..31
        int seg  = tid & 7;           // 0..7, 36 consecutive floats each
        const float* src = w + ((size_t)((cog * 32 + co_l) * 256 + cib * 32)) * 9 + seg * 36;
#pragma unroll
        for (int f4 = 0; f4 < 9; ++f4) {
            float4 v = *(const float4*)(src + f4 * 4);
            uint2 p;
            p.x = (unsigned)f2bf(v.x) | ((unsigned)f2bf(v.y) << 16);
            p.y = (unsigned)f2bf(v.z) | ((unsigned)f2bf(v.w) << 16);
            *(uint2*)(&wlds[co_l][seg * 36 + f4 * 4]) = p;
        }
    }
    __syncthreads();
    for (int idx = tid; idx < 1152; idx += 256) {   // 9j x 2s x 64 lanes
        int lane = idx & 63;
        int s    = (idx >> 6) & 1;
        int j    = idx >> 7;          // 0..8
        int co_l = lane & 31;
        int k0   = s * 16 + (lane >> 5) * 8;
        union { unsigned short us[8]; int4 v; } u;
#pragma unroll
        for (int jj = 0; jj < 8; ++jj)
            u.us[jj] = wlds[co_l][(k0 + jj) * 9 + j];
        int ob = j * 128 + cib * 16 + s * 8 + cog;   // original output block id
        *(int4*)(wa + ((size_t)ob * 64 + lane) * 8) = u.v;
    }
}

// ---------------------------------------------------------------------------
// Conv: implicit-GEMM bf16 MFMA; BOTH operands staged through LDS.
// REVERTED to the empirically-best structure (90.2 us): R1-R4's alternatives
// (global-A, A-pipelining, occupancy doubling) all measured slower; matrix-
// busy ~31 us is invariant, so keep the schedule with the least VMEM pressure.
// Block: 512 thr = 8 waves; tile 256co x 256px (4 rows). Wave: 128co x 64px.
// Grid 256 = 1 block/CU. Phase = one 3x3 tap j of one 32-ci block:
// A chunk (16KB) double-buffered, B tile (per-cib) double-buffered.
// ---------------------------------------------------------------------------
__global__ __launch_bounds__(512, 2) void conv_mfma(const unsigned short* __restrict__ xsqN,
                                                    const unsigned short* __restrict__ wa,
                                                    const float* __restrict__ bias,
                                                    const int* __restrict__ lm,
                                                    const unsigned short* __restrict__ Lval,
                                                    float* __restrict__ out) {
    int pt = blockIdx.x;              // b*16 + hq
    int b  = pt >> 4;
    int h0 = (pt & 15) * 4;
    int tid  = threadIdx.x;
    int lane = tid & 63;
    int wv   = tid >> 6;
    int wy = wv >> 2, wx = wv & 3;    // co half / image row
    int l31 = lane & 31, qh = lane >> 5;

    __shared__ unsigned short Bs[2][6 * 66 * 40];   // 63.4 KB
    __shared__ unsigned short As[2][8192];          // 32 KB

    f32x16 acc[4][2];
#pragma unroll
    for (int mt = 0; mt < 4; ++mt)
#pragma unroll
        for (int nt = 0; nt < 2; ++nt)
#pragma unroll
            for (int r = 0; r < 16; ++r) acc[mt][nt][r] = 0.f;

    int4 sv[4];   // B prefetch registers (live across one cib)
    int4 av0, av1; // A prefetch registers

    // ---- prologue: stage B(cib=0) with rect-max into Bs[0]; A chunk (0,0) into As[0]
    {
#pragma unroll
        for (int t2 = 0; t2 < 4; ++t2) {
            int idx = tid + t2 * 512;
            int4 v = {0, 0, 0, 0};
            if (idx < 1584) {
                int pr = idx / 264; int rem = idx - pr * 264;
                int pc = rem >> 2;  int part = rem & 3;
                int grow = h0 - 1 + pr, gcol = pc - 1;
                if ((unsigned)grow < 64u && (unsigned)gcol < 64u)
                    v = *(const int4*)(xsqN + (((size_t)(b * 64 + grow) * 64 + gcol) * 256 + part * 8));
            }
            sv[t2] = v;
        }
        int l = lm[b * 4 + 0];
        int hm = l >> 6, wm = l & 63;
#pragma unroll
        for (int t2 = 0; t2 < 4; ++t2) {
            int idx = tid + t2 * 512;
            if (idx < 1584) {
                int pr = idx / 264; int rem = idx - pr * 264;
                int pc = rem >> 2;  int part = rem & 3;
                int grow = h0 - 1 + pr, gcol = pc - 1;
                union { int4 v; unsigned short us[8]; } u; u.v = sv[t2];
                bool inb = ((unsigned)grow < 64u) && ((unsigned)gcol < 64u);
                if (inb && grow <= hm && gcol <= wm) {     // quadrant 0: h<=hm, w<=wm
                    union { int4 v; unsigned short us[8]; } Lu;
                    Lu.v = *(const int4*)(Lval + b * 256 + part * 8);
#pragma unroll
                    for (int k = 0; k < 8; ++k)
                        if (Lu.us[k] > u.us[k]) u.us[k] = Lu.us[k];
                }
                *(int4*)(&Bs[0][(pr * 66 + pc) * 40 + part * 8]) = u.v;
            }
        }
        const unsigned short* src = wa + tid * 16;
        av0 = *(const int4*)src;
        av1 = *(const int4*)(src + 8);
        *(int4*)(&As[0][tid * 16])     = av0;
        *(int4*)(&As[0][tid * 16 + 8]) = av1;
    }
    __syncthreads();

    for (int cib = 0; cib < 8; ++cib) {
        for (int j = 0; j < 9; ++j) {
            int p = cib * 9 + j;
            bool hasNext = (p < 71);
            // A prefetch (next phase's 16KB chunk)
            if (hasNext) {
                int jn = j + 1, cibn = cib;
                if (jn == 9) { jn = 0; cibn = cib + 1; }
                const unsigned short* src = wa + ((size_t)(jn * 8 + cibn) << 13) + tid * 16;
                av0 = *(const int4*)src;
                av1 = *(const int4*)(src + 8);
            }
            // B prefetch loads for cib+1 (issued once per cib)
            if (j == 0 && cib < 7) {
                int nc = cib + 1;
#pragma unroll
                for (int t2 = 0; t2 < 4; ++t2) {
                    int idx = tid + t2 * 512;
                    int4 v = {0, 0, 0, 0};
                    if (idx < 1584) {
                        int pr = idx / 264; int rem = idx - pr * 264;
                        int pc = rem >> 2;  int part = rem & 3;
                        int grow = h0 - 1 + pr, gcol = pc - 1;
                        if ((unsigned)grow < 64u && (unsigned)gcol < 64u)
                            v = *(const int4*)(xsqN + (((size_t)(b * 64 + grow) * 64 + gcol) * 256 + nc * 32 + part * 8));
                    }
                    sv[t2] = v;
                }
            }

            // ---- MFMA phase: A from LDS, B from LDS ----
            {
                const unsigned short* Ab = &As[p & 1][0];
                const unsigned short* Bb = &Bs[cib & 1][0];
                int dh = j / 3 - 1, dw = j % 3 - 1;
                int r  = wx + dh + 1;
                int w0 = l31 + dw + 1;
#pragma unroll
                for (int s = 0; s < 2; ++s) {
                    const bf16x8* ap = (const bf16x8*)(Ab + (((s * 8 + wy * 4) * 64 + lane) << 3));
                    bf16x8 a0 = ap[0];
                    bf16x8 a1 = ap[64];
                    bf16x8 a2 = ap[128];
                    bf16x8 a3 = ap[192];
                    bf16x8 b0 = *(const bf16x8*)(Bb + (r * 66 + w0) * 40 + s * 16 + qh * 8);
                    bf16x8 b1 = *(const bf16x8*)(Bb + (r * 66 + w0 + 32) * 40 + s * 16 + qh * 8);
                    acc[0][0] = __builtin_amdgcn_mfma_f32_32x32x16_bf16(a0, b0, acc[0][0], 0, 0, 0);
                    acc[0][1] = __builtin_amdgcn_mfma_f32_32x32x16_bf16(a0, b1, acc[0][1], 0, 0, 0);
                    acc[1][0] = __builtin_amdgcn_mfma_f32_32x32x16_bf16(a1, b0, acc[1][0], 0, 0, 0);
                    acc[1][1] = __builtin_amdgcn_mfma_f32_32x32x16_bf16(a1, b1, acc[1][1], 0, 0, 0);
                    acc[2][0] = __builtin_amdgcn_mfma_f32_32x32x16_bf16(a2, b0, acc[2][0], 0, 0, 0);
                    acc[2][1] = __builtin_amdgcn_mfma_f32_32x32x16_bf16(a2, b1, acc[2][1], 0, 0, 0);
                    acc[3][0] = __builtin_amdgcn_mfma_f32_32x32x16_bf16(a3, b0, acc[3][0], 0, 0, 0);
                    acc[3][1] = __builtin_amdgcn_mfma_f32_32x32x16_bf16(a3, b1, acc[3][1], 0, 0, 0);
                }
            }

            // B rect-max + store for cib+1 (late in the cib, into other buffer)
            if (j == 8 && cib < 7) {
                int nc = cib + 1;
                int l = lm[b * 4 + (nc >> 1)];
                int hm = l >> 6, wm = l & 63;
                bool qhle = (nc >> 1) < 2;
                bool qwle = ((nc >> 1) & 1) == 0;
                unsigned short* Bw = &Bs[(cib + 1) & 1][0];
#pragma unroll
                for (int t2 = 0; t2 < 4; ++t2) {
                    int idx = tid + t2 * 512;
                    if (idx < 1584) {
                        int pr = idx / 264; int rem = idx - pr * 264;
                        int pc = rem >> 2;  int part = rem & 3;
                        int grow = h0 - 1 + pr, gcol = pc - 1;
                        union { int4 v; unsigned short us[8]; } u; u.v = sv[t2];
                        bool inb = ((unsigned)grow < 64u) && ((unsigned)gcol < 64u);
                        bool hok = qhle ? (grow <= hm) : (grow >= hm);
                        bool wok = qwle ? (gcol <= wm) : (gcol >= wm);
                        if (inb && hok && wok) {
                            union { int4 v; unsigned short us[8]; } Lu;
                            Lu.v = *(const int4*)(Lval + b * 256 + nc * 32 + part * 8);
#pragma unroll
                            for (int k = 0; k < 8; ++k)
                                if (Lu.us[k] > u.us[k]) u.us[k] = Lu.us[k];
                        }
                        *(int4*)(&Bw[(pr * 66 + pc) * 40 + part * 8]) = u.v;
                    }
                }
            }
            // A store into the other buffer
            if (hasNext) {
                unsigned short* dst = &As[(p + 1) & 1][tid * 16];
                *(int4*)dst       = av0;
                *(int4*)(dst + 8) = av1;
            }
            __syncthreads();
        }
    }

    // ---- epilogue ----
    int h = h0 + wx;
#pragma unroll
    for (int mt = 0; mt < 4; ++mt) {
#pragma unroll
        for (int nt = 0; nt < 2; ++nt) {
#pragma unroll
            for (int r = 0; r < 16; ++r) {
                int row = (r & 3) + 8 * (r >> 2) + 4 * qh;
                int co  = wy * 128 + mt * 32 + row;
                int w   = nt * 32 + l31;
                out[(((size_t)(b * 256 + co)) * 64 + h) * 64 + w] = acc[mt][nt][r] + bias[co];
            }
        }
    }
}

// ---------------------------------------------------------------------------
extern "C" void kernel_launch(void* const* d_in, const int* in_sizes, int n_in,
                              void* d_out, int out_size, void* d_ws, size_t ws_size,
                              hipStream_t stream) {
    const float* x      = (const float*)d_in[0];
    const float* weight = (const float*)d_in[1];
    const float* bias   = (const float*)d_in[2];
    float* out = (float*)d_out;

    char* ws = (char*)d_ws;
    int*            lmp  = (int*)ws;                         // 64 ints @0
    float*          pval = (float*)(ws + 256);               // 4096 f
    int*            pidx = (int*)(ws + 256 + 16384);         // 4096 i
    unsigned short* Lval = (unsigned short*)(ws + 256 + 32768);  // 4096 ush
    unsigned short* Wa   = (unsigned short*)(ws + 49152);    // 1.18 MB
    unsigned short* xsqN = (unsigned short*)(ws + 49152 + 1179648); // NHWC bf16 33.55 MB

    hipLaunchKernelGGL(fused_energy, dim3(1024), dim3(256), 0, stream, x, xsqN, pval, pidx);
    hipLaunchKernelGGL(energy_final, dim3(64), dim3(64), 0, stream, pval, pidx, lmp, xsqN, Lval);
    hipLaunchKernelGGL(wt_pack, dim3(64), dim3(256), 0, stream, weight, Wa);
    hipLaunchKernelGGL(conv_mfma, dim3(256), dim3(512), 0, stream, xsqN, Wa, bias, lmp, Lval, out);
}

// Round 8
// 189.515 us; speedup vs baseline: 1.1524x; 1.0355x over previous
//
#include <hip/hip_runtime.h>
#include <cstddef>

#define B_   16
#define C_   256
#define HW_  4096

typedef __attribute__((ext_vector_type(8)))  short bf16x8;
typedef __attribute__((ext_vector_type(16))) float f32x16;

static __device__ __forceinline__ unsigned short f2bf(float f) {
    unsigned int u = __float_as_uint(f);
    u += 0x7fffu + ((u >> 16) & 1u);          // RNE
    return (unsigned short)(u >> 16);
}

// ---------------------------------------------------------------------------
// Kernel E v2: fused square + NCHW->NHWC bf16 + per-(b,q,h) energy argmax
// partials. grid = (b,h) = 1024 blocks x 256 thr. (verified R5)
// ---------------------------------------------------------------------------
__global__ __launch_bounds__(256) void fused_energy(const float* __restrict__ x,
                                                    unsigned short* __restrict__ xsqN,
                                                    float* __restrict__ pval,
                                                    int* __restrict__ pidx) {
    int blk = blockIdx.x;
    int b = blk >> 6, h = blk & 63;
    int tid = threadIdx.x;
    int tl  = tid >> 4;           // 0..15 channel-lane group
    int w4  = (tid & 15) << 2;    // w base 0,4,...,60
    int wv  = tid >> 6;           // wave 0..3
    __shared__ float earr[4][4][64];            // [wave][q][w]
    __shared__ unsigned short tile[64][264];    // row stride 264 ush = 528B
    const float* xb = x + (size_t)b * C_ * HW_ + h * 64 + w4;

    float e[4][4];                // [quadrant][ww]
#pragma unroll
    for (int q = 0; q < 4; ++q)
#pragma unroll
        for (int ww = 0; ww < 4; ++ww) e[q][ww] = 0.f;

#pragma unroll
    for (int i = 0; i < 4; ++i) {             // quadrant = i (compile-time)
        int c4 = tl * 4 + 64 * i;             // 4 consecutive channels
        float sq[4][4];                       // [k=channel][ww]
#pragma unroll
        for (int k = 0; k < 4; ++k) {
            float4 v = *(const float4*)(xb + (size_t)(c4 + k) * HW_);
            sq[k][0] = v.x * v.x; sq[k][1] = v.y * v.y;
            sq[k][2] = v.z * v.z; sq[k][3] = v.w * v.w;
            e[i][0] += sq[k][0]; e[i][1] += sq[k][1];
            e[i][2] += sq[k][2]; e[i][3] += sq[k][3];
        }
#pragma unroll
        for (int ww = 0; ww < 4; ++ww) {      // pack 4 channels -> ushort4
            uint2 p;
            p.x = (unsigned)f2bf(sq[0][ww]) | ((unsigned)f2bf(sq[1][ww]) << 16);
            p.y = (unsigned)f2bf(sq[2][ww]) | ((unsigned)f2bf(sq[3][ww]) << 16);
            *(uint2*)(&tile[w4 + ww][c4]) = p;
        }
    }

    // wave-local reduce over the 4 tl-groups within this wave (tid bits 4,5)
#pragma unroll
    for (int q = 0; q < 4; ++q)
#pragma unroll
        for (int ww = 0; ww < 4; ++ww) {
            float v = e[q][ww];
            v += __shfl_xor(v, 16);
            v += __shfl_xor(v, 32);
            e[q][ww] = v;
        }
    if ((tid & 48) == 0) {
#pragma unroll
        for (int q = 0; q < 4; ++q) {
            float4 v; v.x = e[q][0]; v.y = e[q][1]; v.z = e[q][2]; v.w = e[q][3];
            *(float4*)&earr[wv][q][w4] = v;
        }
    }
    __syncthreads();

    // contiguous NHWC stores: 32 lanes cover one 512B row segment
    size_t base = (size_t)(b * 64 + h) * 64 * 256;
#pragma unroll
    for (int it = 0; it < 8; ++it) {
        int row  = it * 8 + (tid >> 5);
        int col8 = (tid & 31) * 8;
        *(int4*)(xsqN + base + (size_t)row * 256 + col8) = *(int4*)&tile[row][col8];
    }

    int q = tid >> 6;
    int w = tid & 63;
    float ev = earr[0][q][w] + earr[1][q][w] + earr[2][q][w] + earr[3][q][w];
    int ix = h * 64 + w;
#pragma unroll
    for (int off = 32; off; off >>= 1) {
        float ov = __shfl_down(ev, off);
        int   oi = __shfl_down(ix, off);
        if (ov > ev || (ov == ev && oi < ix)) { ev = ov; ix = oi; }
    }
    if ((tid & 63) == 0) {
        pval[(b * 64 + h) * 4 + q] = ev;
        pidx[(b * 64 + h) * 4 + q] = ix;
    }
}

// ---------------------------------------------------------------------------
// Final argmax over h per (b,q) FUSED with landmark value gather.
// grid = 64 blocks (b*4+q) x 64 thr. (verified R5)
// ---------------------------------------------------------------------------
__global__ __launch_bounds__(64) void energy_final(const float* __restrict__ pval,
                                                   const int* __restrict__ pidx,
                                                   int* __restrict__ lm,
                                                   const unsigned short* __restrict__ xsqN,
                                                   unsigned short* __restrict__ Lval) {
    int bq = blockIdx.x;
    int b = bq >> 2, q = bq & 3;
    int t = threadIdx.x;
    float ev = pval[(b * 64 + t) * 4 + q];
    int   ix = pidx[(b * 64 + t) * 4 + q];
#pragma unroll
    for (int off = 32; off; off >>= 1) {
        float ov = __shfl_down(ev, off);
        int   oi = __shfl_down(ix, off);
        if (ov > ev || (ov == ev && oi < ix)) { ev = ov; ix = oi; }
    }
    int ix0 = __shfl(ix, 0);
    if (t == 0) lm[bq] = ix0;
    Lval[b * 256 + q * 64 + t] =
        xsqN[((size_t)((b * 64 + (ix0 >> 6)) * 64 + (ix0 & 63))) * 256 + q * 64 + t];
}

// ---------------------------------------------------------------------------
// Weight pack v3 -> fragment-ordered bf16, CIB-MAJOR chunk order:
//   chunk c' = cib*9 + j at offset c'*8192 ushorts (16KB).
// So conv phase ph (= cib*3+sub, 3 taps) reads the CONTIGUOUS 48KB
// [3ph, 3ph+3)*8192 — one linear region for global_load_lds staging.
// Within-chunk fragment layout unchanged: (s*8 + cog)*64*8 + lane*8.
// grid = 64 blocks (cog*8+cib) x 256 thr.
// ---------------------------------------------------------------------------
__global__ __launch_bounds__(256) void wt_pack(const float* __restrict__ w,
                                               unsigned short* __restrict__ wa) {
    int blk = blockIdx.x;
    int cog = blk >> 3, cib = blk & 7;
    int tid = threadIdx.x;
    __shared__ unsigned short wlds[32][292];   // [co_l][cc*9+j], pad 288->292
    {
        int co_l = tid >> 3;          // 0..31
        int seg  = tid & 7;           // 0..7, 36 consecutive floats each
        const float* src = w + ((size_t)((cog * 32 + co_l) * 256 + cib * 32)) * 9 + seg * 36;
#pragma unroll
        for (int f4 = 0; f4 < 9; ++f4) {
            float4 v = *(const float4*)(src + f4 * 4);
            uint2 p;
            p.x = (unsigned)f2bf(v.x) | ((unsigned)f2bf(v.y) << 16);
            p.y = (unsigned)f2bf(v.z) | ((unsigned)f2bf(v.w) << 16);
            *(uint2*)(&wlds[co_l][seg * 36 + f4 * 4]) = p;
        }
    }
    __syncthreads();
    for (int idx = tid; idx < 1152; idx += 256) {   // 9j x 2s x 64 lanes
        int lane = idx & 63;
        int s    = (idx >> 6) & 1;
        int j    = idx >> 7;          // 0..8
        int co_l = lane & 31;
        int k0   = s * 16 + (lane >> 5) * 8;
        union { unsigned short us[8]; int4 v; } u;
#pragma unroll
        for (int jj = 0; jj < 8; ++jj)
            u.us[jj] = wlds[co_l][(k0 + jj) * 9 + j];
        int ob = (cib * 9 + j) * 16 + s * 8 + cog;   // cib-major chunk order
        *(int4*)(wa + ((size_t)ob * 64 + lane) * 8) = u.v;
    }
}

// ---------------------------------------------------------------------------
// B-tile helpers (512-thread block): register load, then rect-max + LDS store.
// ---------------------------------------------------------------------------
static __device__ __forceinline__ void load_B(int4 sv[4],
                                              const unsigned short* __restrict__ xsqN,
                                              int b, int h0, int nc, int tid) {
#pragma unroll
    for (int t2 = 0; t2 < 4; ++t2) {
        int idx = tid + t2 * 512;
        int4 v = {0, 0, 0, 0};
        if (idx < 1584) {
            int pr = idx / 264; int rem = idx - pr * 264;
            int pc = rem >> 2;  int part = rem & 3;
            int grow = h0 - 1 + pr, gcol = pc - 1;
            if ((unsigned)grow < 64u && (unsigned)gcol < 64u)
                v = *(const int4*)(xsqN + (((size_t)(b * 64 + grow) * 64 + gcol) * 256 + nc * 32 + part * 8));
        }
        sv[t2] = v;
    }
}

static __device__ __forceinline__ void store_B(const int4 sv[4],
                                               unsigned short* __restrict__ Bw,
                                               const unsigned short* __restrict__ Lval,
                                               const int* __restrict__ lm,
                                               int b, int h0, int nc, int tid) {
    int l = lm[b * 4 + (nc >> 1)];
    int hm = l >> 6, wm = l & 63;
    bool qhle = (nc >> 1) < 2;          // quadrants 0,1: h <= hm
    bool qwle = ((nc >> 1) & 1) == 0;   // quadrants 0,2: w <= wm
#pragma unroll
    for (int t2 = 0; t2 < 4; ++t2) {
        int idx = tid + t2 * 512;
        if (idx < 1584) {
            int pr = idx / 264; int rem = idx - pr * 264;
            int pc = rem >> 2;  int part = rem & 3;
            int grow = h0 - 1 + pr, gcol = pc - 1;
            union { int4 v; unsigned short us[8]; } u; u.v = sv[t2];
            bool inb = ((unsigned)grow < 64u) && ((unsigned)gcol < 64u);
            bool hok = qhle ? (grow <= hm) : (grow >= hm);
            bool wok = qwle ? (gcol <= wm) : (gcol >= wm);
            if (inb && hok && wok) {
                union { int4 v; unsigned short us[8]; } Lu;
                Lu.v = *(const int4*)(Lval + b * 256 + nc * 32 + part * 8);
#pragma unroll
                for (int k = 0; k < 8; ++k)
                    if (Lu.us[k] > u.us[k]) u.us[k] = Lu.us[k];  // bf16 >=0: bit-compare valid
            }
            *(int4*)(&Bw[(pr * 66 + pc) * 40 + part * 8]) = u.v;
        }
    }
}

// ---------------------------------------------------------------------------
// Conv v5: implicit-GEMM bf16 MFMA, 3-TAP PHASES + global_load_lds A staging.
//   Diagnosis (R0-R4): phase ≈ 2900 cy of which only 1024 cy is MFMA; the
//   ~1900 cy A-stage/barrier overhead is per-PHASE, paid 72x. Fix: merge 3
//   taps per phase -> 24 phases x (3072 cy MFMA + overhead); overhead
//   amortized 3x, and the A/B prefetch latency now has 3072 cy of MFMA cover
//   before the barrier drain.
//   A staged by DMA: __builtin_amdgcn_global_load_lds width=16 (linear
//   wave-uniform-base + lane*16 dest — exactly this pattern). No VGPR
//   round-trip, no ds_write stream. Source contiguous thanks to wt_pack v3.
//   B: unchanged proven pattern (reg prefetch at sub==0, rect-max store at
//   sub==2 into other buffer, one barrier per phase).
// LDS: As 2x48KB + Bs 2x31.7KB = 161.7 KB (<= 160 KiB/CU cap, 1 block/CU).
// Block: 512 thr = 8 waves; tile 256co x 256px. Wave: 128co x 64px. Grid 256.
// ---------------------------------------------------------------------------
__global__ __launch_bounds__(512, 2) void conv_mfma(const unsigned short* __restrict__ xsqN,
                                                    const unsigned short* __restrict__ wa,
                                                    const float* __restrict__ bias,
                                                    const int* __restrict__ lm,
                                                    const unsigned short* __restrict__ Lval,
                                                    float* __restrict__ out) {
    int pt = blockIdx.x;              // b*16 + hq
    int b  = pt >> 4;
    int h0 = (pt & 15) * 4;
    int tid  = threadIdx.x;
    int lane = tid & 63;
    int wv   = tid >> 6;
    int wy = wv >> 2, wx = wv & 3;    // co half / image row
    int l31 = lane & 31, qh = lane >> 5;

    __shared__ unsigned short Bs[2][6 * 66 * 40];   // 63.4 KB
    __shared__ unsigned short As[2][3 * 8192];      // 98.3 KB (3 taps/phase)

    f32x16 acc[4][2];
#pragma unroll
    for (int mt = 0; mt < 4; ++mt)
#pragma unroll
        for (int nt = 0; nt < 2; ++nt)
#pragma unroll
            for (int r = 0; r < 16; ++r) acc[mt][nt][r] = 0.f;

    int4 sv[4];   // B prefetch registers (live across one cib)

    // ---- prologue: B(cib=0) into Bs[0]; A phase 0 (chunks 0..2) into As[0]
    load_B(sv, xsqN, b, h0, 0, tid);
    {
        // wave wv stages bytes [wv*6144, wv*6144+6144) of the 48KB phase chunk
        const unsigned short* s0 = wa + wv * 3072 + lane * 8;
#pragma unroll
        for (int k = 0; k < 6; ++k)
            __builtin_amdgcn_global_load_lds(s0 + k * 512, &As[0][wv * 3072 + k * 512], 16, 0, 0);
    }
    store_B(sv, &Bs[0][0], Lval, lm, b, h0, 0, tid);
    __syncthreads();

    for (int cib = 0; cib < 8; ++cib) {
#pragma unroll
        for (int sub = 0; sub < 3; ++sub) {
            int ph = cib * 3 + sub;

            // ---- A DMA stage for next phase (issued first: max MFMA cover)
            if (ph < 23) {
                const unsigned short* s0 = wa + (size_t)(ph + 1) * 24576 + wv * 3072 + lane * 8;
                unsigned short* d0 = &As[(ph + 1) & 1][wv * 3072];
#pragma unroll
                for (int k = 0; k < 6; ++k)
                    __builtin_amdgcn_global_load_lds(s0 + k * 512, d0 + k * 512, 16, 0, 0);
            }
            // ---- B global prefetch for cib+1 (once per cib)
            if (sub == 0 && cib < 7)
                load_B(sv, xsqN, b, h0, cib + 1, tid);

            // ---- MFMA: 3 taps from As[ph&1], B from Bs[cib&1]
            const unsigned short* Ab = &As[ph & 1][0];
            const unsigned short* Bb = &Bs[cib & 1][0];
#pragma unroll
            for (int tt = 0; tt < 3; ++tt) {
                int j  = sub * 3 + tt;            // compile-time (sub,tt unrolled)
                int r  = wx + j / 3;              // dh+1
                int w0 = l31 + j % 3;             // dw+1
                const unsigned short* Bp = Bb + (r * 66 + w0) * 40 + qh * 8;
                const unsigned short* At = Ab + tt * 8192;
#pragma unroll
                for (int s = 0; s < 2; ++s) {
                    const bf16x8* ap = (const bf16x8*)(At + (((s * 8 + wy * 4) * 64 + lane) << 3));
                    bf16x8 a0 = ap[0];
                    bf16x8 a1 = ap[64];
                    bf16x8 a2 = ap[128];
                    bf16x8 a3 = ap[192];
                    bf16x8 b0 = *(const bf16x8*)(Bp + s * 16);
                    bf16x8 b1 = *(const bf16x8*)(Bp + 1280 + s * 16);
                    acc[0][0] = __builtin_amdgcn_mfma_f32_32x32x16_bf16(a0, b0, acc[0][0], 0, 0, 0);
                    acc[0][1] = __builtin_amdgcn_mfma_f32_32x32x16_bf16(a0, b1, acc[0][1], 0, 0, 0);
                    acc[1][0] = __builtin_amdgcn_mfma_f32_32x32x16_bf16(a1, b0, acc[1][0], 0, 0, 0);
                    acc[1][1] = __builtin_amdgcn_mfma_f32_32x32x16_bf16(a1, b1, acc[1][1], 0, 0, 0);
                    acc[2][0] = __builtin_amdgcn_mfma_f32_32x32x16_bf16(a2, b0, acc[2][0], 0, 0, 0);
                    acc[2][1] = __builtin_amdgcn_mfma_f32_32x32x16_bf16(a2, b1, acc[2][1], 0, 0, 0);
                    acc[3][0] = __builtin_amdgcn_mfma_f32_32x32x16_bf16(a3, b0, acc[3][0], 0, 0, 0);
                    acc[3][1] = __builtin_amdgcn_mfma_f32_32x32x16_bf16(a3, b1, acc[3][1], 0, 0, 0);
                }
            }

            // ---- B rect-max + store for cib+1 (into other buffer, last sub)
            if (sub == 2 && cib < 7)
                store_B(sv, &Bs[(cib + 1) & 1][0], Lval, lm, b, h0, cib + 1, tid);

            __syncthreads();
        }
    }

    // ---- epilogue ----
    int h = h0 + wx;
#pragma unroll
    for (int mt = 0; mt < 4; ++mt) {
#pragma unroll
        for (int nt = 0; nt < 2; ++nt) {
#pragma unroll
            for (int r = 0; r < 16; ++r) {
                int row = (r & 3) + 8 * (r >> 2) + 4 * qh;
                int co  = wy * 128 + mt * 32 + row;
                int w   = nt * 32 + l31;
                out[(((size_t)(b * 256 + co)) * 64 + h) * 64 + w] = acc[mt][nt][r] + bias[co];
            }
        }
    }
}

// ---------------------------------------------------------------------------
extern "C" void kernel_launch(void* const* d_in, const int* in_sizes, int n_in,
                              void* d_out, int out_size, void* d_ws, size_t ws_size,
                              hipStream_t stream) {
    const float* x      = (const float*)d_in[0];
    const float* weight = (const float*)d_in[1];
    const float* bias   = (const float*)d_in[2];
    float* out = (float*)d_out;

    char* ws = (char*)d_ws;
    int*            lmp  = (int*)ws;                         // 64 ints @0
    float*          pval = (float*)(ws + 256);               // 4096 f
    int*            pidx = (int*)(ws + 256 + 16384);         // 4096 i
    unsigned short* Lval = (unsigned short*)(ws + 256 + 32768);  // 4096 ush
    unsigned short* Wa   = (unsigned short*)(ws + 49152);    // 1.18 MB
    unsigned short* xsqN = (unsigned short*)(ws + 49152 + 1179648); // NHWC bf16 33.55 MB

    hipLaunchKernelGGL(fused_energy, dim3(1024), dim3(256), 0, stream, x, xsqN, pval, pidx);
    hipLaunchKernelGGL(energy_final, dim3(64), dim3(64), 0, stream, pval, pidx, lmp, xsqN, Lval);
    hipLaunchKernelGGL(wt_pack, dim3(64), dim3(256), 0, stream, weight, Wa);
    hipLaunchKernelGGL(conv_mfma, dim3(256), dim3(512), 0, stream, xsqN, Wa, bias, lmp, Lval, out);
}